// Round 3
// baseline (597.514 us; speedup 1.0000x reference)
//
#include <hip/hip_runtime.h>
#include <math.h>

#define D 64
#define K 4096
#define NCHUNK 4
#define KC (K / NCHUNK)

typedef float f32x2 __attribute__((ext_vector_type(2)));

// ---------------------------------------------------------------------------
// e_sq[k] = sum_d emb[k][d]^2
// ---------------------------------------------------------------------------
__global__ __launch_bounds__(256) void esq_kernel(const float* __restrict__ emb,
                                                  float* __restrict__ e_sq) {
  int k = blockIdx.x * 256 + threadIdx.x;
  if (k >= K) return;
  const float* e = emb + (size_t)k * D;
  float s = 0.f;
#pragma unroll
  for (int d = 0; d < D; ++d) s = fmaf(e[d], e[d], s);
  e_sq[k] = s;
}

// ---------------------------------------------------------------------------
// Per-row argmin over one K-chunk. One thread = one row.
// z[] is pinned into VGPRs via an opaque asm constraint: rounds 1-2 showed
// the compiler rematerializes invariant global loads inside the k-loop
// (VGPR_Count 36/44 < the 64 regs z needs), making the loop VMEM-issue
// bound. Pinning forces z residency; emb stays wave-uniform -> s_load into
// the SGPR operand of v_pk_fma_f32.
// Strict '<' ascending k => first-occurrence argmin like jnp.argmin.
// ---------------------------------------------------------------------------
__global__ __launch_bounds__(256, 4) void dist_kernel(const float* __restrict__ z_e,
                                                      const float* __restrict__ emb,
                                                      const float* __restrict__ e_sq,
                                                      float* __restrict__ pmin,
                                                      int* __restrict__ pidx) {
  const int row = blockIdx.x * 256 + threadIdx.x;
  const int chunk = blockIdx.y;
  const int k0 = chunk * KC;

  f32x2 z[D / 2];
  const f32x2* zp = (const f32x2*)(z_e + (size_t)row * D);
#pragma unroll
  for (int i = 0; i < D / 2; ++i) z[i] = zp[i];

  f32x2 zs = {0.f, 0.f};
#pragma unroll
  for (int i = 0; i < D / 2; ++i) zs = __builtin_elementwise_fma(z[i], z[i], zs);
  const float zsq = zs.x + zs.y;

  // Pin: make each z pair an opaque VGPR value the compiler cannot
  // rematerialize from memory inside the k-loop.
#pragma unroll
  for (int i = 0; i < D / 2; ++i) asm volatile("" : "+v"(z[i]));

  float best = __builtin_inff();
  int bidx = k0;

  for (int k = k0; k < k0 + KC; k += 4) {
    const f32x2* e0 = (const f32x2*)(emb + (size_t)k * D);
    f32x2 a0 = {0.f, 0.f}, a1 = {0.f, 0.f}, a2 = {0.f, 0.f}, a3 = {0.f, 0.f};
#pragma unroll
    for (int i = 0; i < D / 2; ++i) {
      f32x2 zi = z[i];
      a0 = __builtin_elementwise_fma(e0[i], zi, a0);
      a1 = __builtin_elementwise_fma(e0[D / 2 + i], zi, a1);
      a2 = __builtin_elementwise_fma(e0[D + i], zi, a2);
      a3 = __builtin_elementwise_fma(e0[3 * D / 2 + i], zi, a3);
    }
    float q0 = (zsq - 2.f * (a0.x + a0.y)) + e_sq[k + 0];
    float q1 = (zsq - 2.f * (a1.x + a1.y)) + e_sq[k + 1];
    float q2 = (zsq - 2.f * (a2.x + a2.y)) + e_sq[k + 2];
    float q3 = (zsq - 2.f * (a3.x + a3.y)) + e_sq[k + 3];
    if (q0 < best) { best = q0; bidx = k; }
    if (q1 < best) { best = q1; bidx = k + 1; }
    if (q2 < best) { best = q2; bidx = k + 2; }
    if (q3 < best) { best = q3; bidx = k + 3; }
  }
  pmin[(size_t)row * NCHUNK + chunk] = best;
  pidx[(size_t)row * NCHUNK + chunk] = bidx;
}

// ---------------------------------------------------------------------------
// Combine chunk argmins, gather z_q, write z_q_st + indices, accumulate
// per-block loss partials and code-usage histogram. One 64-lane wave per row.
// ---------------------------------------------------------------------------
__global__ __launch_bounds__(256) void combine_kernel(const float* __restrict__ z_e,
                                                      const float* __restrict__ emb,
                                                      const float* __restrict__ pmin,
                                                      const int* __restrict__ pidx,
                                                      float* __restrict__ out_zq,
                                                      float* __restrict__ out_idx,
                                                      int* __restrict__ counts,
                                                      float* __restrict__ block_loss) {
  const int tid = threadIdx.x;
  const int wave = tid >> 6;
  const int lane = tid & 63;
  const int row = blockIdx.x * 4 + wave;

  // chunks ascending, strict '<' => global first-occurrence argmin
  float best = pmin[(size_t)row * NCHUNK + 0];
  int bidx = pidx[(size_t)row * NCHUNK + 0];
#pragma unroll
  for (int c = 1; c < NCHUNK; ++c) {
    float m = pmin[(size_t)row * NCHUNK + c];
    int ix = pidx[(size_t)row * NCHUNK + c];
    if (m < best) { best = m; bidx = ix; }
  }

  float ze = z_e[(size_t)row * D + lane];
  float zq = emb[(size_t)bidx * D + lane];
  float st = ze + (zq - ze);  // straight-through, same formula as reference
  out_zq[(size_t)row * D + lane] = st;

  float diff = zq - ze;
  float sq = diff * diff;
#pragma unroll
  for (int off = 32; off > 0; off >>= 1) sq += __shfl_down(sq, off);

  __shared__ float ls[4];
  if (lane == 0) {
    ls[wave] = sq;
    out_idx[row] = (float)bidx;
    atomicAdd(&counts[bidx], 1);
  }
  __syncthreads();
  if (tid == 0) block_loss[blockIdx.x] = ls[0] + ls[1] + ls[2] + ls[3];
}

// ---------------------------------------------------------------------------
// Final scalars: commitment loss, perplexity, n_active. Single block.
// ---------------------------------------------------------------------------
__global__ __launch_bounds__(1024) void stats_kernel(const float* __restrict__ block_loss,
                                                     int nblocks,
                                                     const int* __restrict__ counts,
                                                     float* __restrict__ out_scalars,
                                                     int N) {
  const int tid = threadIdx.x;
  const int wave = tid >> 6;
  const int lane = tid & 63;

  float lsum = 0.f;
  for (int i = tid; i < nblocks; i += 1024) lsum += block_loss[i];

  float ent = 0.f;
  int act = 0;
  const float invN = 1.0f / (float)N;
  for (int k = tid; k < K; k += 1024) {
    float p = (float)counts[k] * invN;
    ent += p * logf(p + 1e-10f);
    act += (p > 0.001f) ? 1 : 0;
  }

#pragma unroll
  for (int off = 32; off > 0; off >>= 1) {
    lsum += __shfl_down(lsum, off);
    ent += __shfl_down(ent, off);
    act += __shfl_down(act, off);
  }

  __shared__ float sl[16], se[16];
  __shared__ int sa[16];
  if (lane == 0) { sl[wave] = lsum; se[wave] = ent; sa[wave] = act; }
  __syncthreads();
  if (tid == 0) {
    float L = 0.f, E = 0.f;
    int A = 0;
#pragma unroll
    for (int w = 0; w < 16; ++w) { L += sl[w]; E += se[w]; A += sa[w]; }
    out_scalars[0] = 0.25f * L / ((float)N * (float)D);  // commitment loss
    out_scalars[1] = expf(-E);                            // perplexity
    out_scalars[2] = (float)A;                            // n_active
  }
}

extern "C" void kernel_launch(void* const* d_in, const int* in_sizes, int n_in,
                              void* d_out, int out_size, void* d_ws, size_t ws_size,
                              hipStream_t stream) {
  const float* z_e = (const float*)d_in[0];
  const float* emb = (const float*)d_in[1];
  const int N = in_sizes[0] / D;  // 65536

  float* out = (float*)d_out;
  float* out_zq = out;
  float* out_idx = out + (size_t)N * D;
  float* out_scalars = out + (size_t)N * (D + 1);

  char* ws = (char*)d_ws;
  int* counts = (int*)ws;                                        // 16 KB
  float* e_sq = (float*)(ws + 16384);                            // 16 KB
  float* pmin = (float*)(ws + 32768);                            // N*4*4 B
  int* pidx = (int*)(ws + 32768 + (size_t)N * NCHUNK * 4);       // N*4*4 B
  float* block_loss =
      (float*)(ws + 32768 + 2 * (size_t)N * NCHUNK * 4);         // (N/4)*4 B

  hipMemsetAsync(counts, 0, K * sizeof(int), stream);

  esq_kernel<<<K / 256, 256, 0, stream>>>(emb, e_sq);
  dist_kernel<<<dim3(N / 256, NCHUNK), 256, 0, stream>>>(z_e, emb, e_sq, pmin, pidx);
  combine_kernel<<<N / 4, 256, 0, stream>>>(z_e, emb, pmin, pidx, out_zq, out_idx,
                                            counts, block_loss);
  stats_kernel<<<1, 1024, 0, stream>>>(block_loss, N / 4, counts, out_scalars, N);
}

// Round 4
// 479.738 us; speedup vs baseline: 1.2455x; 1.2455x over previous
//
#include <hip/hip_runtime.h>
#include <math.h>

#define D 64
#define K 4096
#define MARGIN 0.0625f

typedef float f32x4 __attribute__((ext_vector_type(4)));
typedef short bf16x8 __attribute__((ext_vector_type(8)));
typedef short s16x4 __attribute__((ext_vector_type(4)));

// RNE fp32 -> bf16 (bit pattern as ushort)
static __device__ inline unsigned short f2bf(float x) {
  unsigned u = __builtin_bit_cast(unsigned, x);
  unsigned r = (u + 0x7FFF + ((u >> 16) & 1)) >> 16;
  return (unsigned short)r;
}
static __device__ inline float bf2f(unsigned short s) {
  unsigned u = ((unsigned)s) << 16;
  return __builtin_bit_cast(float, u);
}

// ---------------------------------------------------------------------------
// e_sq[k] = sum_d emb[k][d]^2  (exact fp32; used by both approx and fallback)
// ---------------------------------------------------------------------------
__global__ __launch_bounds__(256) void esq_kernel(const float* __restrict__ emb,
                                                  float* __restrict__ e_sq) {
  int k = blockIdx.x * 256 + threadIdx.x;
  if (k >= K) return;
  const float* e = emb + (size_t)k * D;
  float s = 0.f;
#pragma unroll
  for (int d = 0; d < D; ++d) s = fmaf(e[d], e[d], s);
  e_sq[k] = s;
}

// ---------------------------------------------------------------------------
// Split emb into bf16 hi/lo arrays (K*D each).
// ---------------------------------------------------------------------------
__global__ __launch_bounds__(256) void esplit_kernel(const float* __restrict__ emb,
                                                     unsigned short* __restrict__ e_hi,
                                                     unsigned short* __restrict__ e_lo) {
  int i4 = blockIdx.x * 256 + threadIdx.x;  // one float4 per thread
  if (i4 >= K * D / 4) return;
  const f32x4 v = *(const f32x4*)(emb + (size_t)i4 * 4);
  s16x4 h, l;
#pragma unroll
  for (int j = 0; j < 4; ++j) {
    float x = v[j];
    unsigned short hb = f2bf(x);
    h[j] = (short)hb;
    l[j] = (short)f2bf(x - bf2f(hb));
  }
  *(s16x4*)(e_hi + (size_t)i4 * 4) = h;
  *(s16x4*)(e_lo + (size_t)i4 * 4) = l;
}

// ---------------------------------------------------------------------------
// MFMA distance/argmin kernel.
// Block = 4 waves; wave handles 32 rows (2 sets of 16); scans all 4096 codes
// in 256 chunks of 16. dot via 3-pass split-bf16 16x16x32 MFMA; rank on
// q = esq[c] - 2*dot (zsq drops out of argmin). Tracks best/second/argmin
// per row; gap < MARGIN rows are exactly re-resolved in combine_kernel.
// B staged in LDS in fragment order (lane*16B, conflict-free), double-buffered.
// A-frag layout: A[m=lane&15][k=(lane>>4)*8+j]; B same with n=lane&15 (B^T).
// C/D: col(n)=lane&15, row(m)=(lane>>4)*4+reg.
// ---------------------------------------------------------------------------
__global__ __launch_bounds__(256, 2) void dist_kernel(const float* __restrict__ z_e,
                                                      const unsigned short* __restrict__ e_hi,
                                                      const unsigned short* __restrict__ e_lo,
                                                      const float* __restrict__ esq,
                                                      int* __restrict__ best_idx,
                                                      float* __restrict__ gapv) {
  __shared__ short lds[2][4][512];  // [buf][frag][lane*8 shorts] = 8 KB

  const int tid = threadIdx.x;
  const int wv = tid >> 6;
  const int lane = tid & 63;
  const int quad = lane >> 4;
  const int col = lane & 15;
  const int rowbase = blockIdx.x * 128 + wv * 32;

  // staging role: this thread stages fragment f = wv each chunk
  const int sf = wv;               // 0:hi k0, 1:hi k1, 2:lo k0, 3:lo k1
  const unsigned short* sbase = (sf >= 2) ? e_lo : e_hi;
  const int sdim = (sf & 1) * 32 + quad * 8;

  // ---- A fragments: load z rows, split to bf16 hi/lo on the fly ----
  bf16x8 a_hi[2][2], a_lo[2][2];
#pragma unroll
  for (int s = 0; s < 2; ++s) {
#pragma unroll
    for (int t = 0; t < 2; ++t) {
      const float* zr = z_e + (size_t)(rowbase + s * 16 + col) * D + t * 32 + quad * 8;
      f32x4 u0 = *(const f32x4*)zr;
      f32x4 u1 = *(const f32x4*)(zr + 4);
#pragma unroll
      for (int j = 0; j < 8; ++j) {
        float x = (j < 4) ? u0[j] : u1[j - 4];
        unsigned short hb = f2bf(x);
        a_hi[s][t][j] = (short)hb;
        a_lo[s][t][j] = (short)f2bf(x - bf2f(hb));
      }
    }
  }

  float best[8], second[8];
  int bidx[8];
#pragma unroll
  for (int i = 0; i < 8; ++i) {
    best[i] = __builtin_inff();
    second[i] = __builtin_inff();
    bidx[i] = 0;
  }

  // ---- stage chunk 0 ----
  {
    const unsigned short* src = sbase + (size_t)(0 * 16 + col) * D + sdim;
    *(bf16x8*)&lds[0][sf][lane * 8] = *(const bf16x8*)src;
  }
  __syncthreads();

  int buf = 0;
  for (int chunk = 0; chunk < K / 16; ++chunk) {
    // stage next chunk into the other buffer (overlaps with compute)
    if (chunk + 1 < K / 16) {
      const unsigned short* src = sbase + (size_t)((chunk + 1) * 16 + col) * D + sdim;
      *(bf16x8*)&lds[buf ^ 1][sf][lane * 8] = *(const bf16x8*)src;
    }

    const float esql = esq[chunk * 16 + col];
    const int code = chunk * 16 + col;

    bf16x8 bh0 = *(const bf16x8*)&lds[buf][0][lane * 8];
    bf16x8 bh1 = *(const bf16x8*)&lds[buf][1][lane * 8];
    bf16x8 bl0 = *(const bf16x8*)&lds[buf][2][lane * 8];
    bf16x8 bl1 = *(const bf16x8*)&lds[buf][3][lane * 8];

#pragma unroll
    for (int s = 0; s < 2; ++s) {
      f32x4 acc = {0.f, 0.f, 0.f, 0.f};
      acc = __builtin_amdgcn_mfma_f32_16x16x32_bf16(a_hi[s][0], bh0, acc, 0, 0, 0);
      acc = __builtin_amdgcn_mfma_f32_16x16x32_bf16(a_lo[s][0], bh0, acc, 0, 0, 0);
      acc = __builtin_amdgcn_mfma_f32_16x16x32_bf16(a_hi[s][0], bl0, acc, 0, 0, 0);
      acc = __builtin_amdgcn_mfma_f32_16x16x32_bf16(a_hi[s][1], bh1, acc, 0, 0, 0);
      acc = __builtin_amdgcn_mfma_f32_16x16x32_bf16(a_lo[s][1], bh1, acc, 0, 0, 0);
      acc = __builtin_amdgcn_mfma_f32_16x16x32_bf16(a_hi[s][1], bl1, acc, 0, 0, 0);
#pragma unroll
      for (int r = 0; r < 4; ++r) {
        float q = fmaf(-2.f, acc[r], esql);
        int i = s * 4 + r;
        float ob = best[i];
        best[i] = fminf(ob, q);
        second[i] = fminf(second[i], fmaxf(ob, q));
        bidx[i] = (q < ob) ? code : bidx[i];
      }
    }
    __syncthreads();
    buf ^= 1;
  }

  // ---- cross-lane merge over the 16 codes (lanes differing in col) ----
#pragma unroll
  for (int i = 0; i < 8; ++i) {
    float b = best[i], s2 = second[i];
    int ix = bidx[i];
#pragma unroll
    for (int off = 1; off < 16; off <<= 1) {
      float ob = __shfl_xor(b, off);
      float os = __shfl_xor(s2, off);
      int oi = __shfl_xor(ix, off);
      float nb = fminf(b, ob);
      float ns = fminf(fminf(s2, os), fmaxf(b, ob));
      ix = (ob < b) ? oi : ix;
      b = nb;
      s2 = ns;
    }
    best[i] = b;
    second[i] = s2;
    bidx[i] = ix;
  }

  if (col == 0) {
#pragma unroll
    for (int s = 0; s < 2; ++s) {
#pragma unroll
      for (int r = 0; r < 4; ++r) {
        int i = s * 4 + r;
        int g = rowbase + s * 16 + quad * 4 + r;
        best_idx[g] = bidx[i];
        gapv[g] = second[i] - best[i];
      }
    }
  }
}

// ---------------------------------------------------------------------------
// Per-row finalize: exact fp32 rescan for ambiguous rows (gap < MARGIN),
// then gather z_q, write z_q_st + indices, loss partials, histogram.
// One 64-lane wave per row.
// ---------------------------------------------------------------------------
__global__ __launch_bounds__(256) void combine_kernel(const float* __restrict__ z_e,
                                                      const float* __restrict__ emb,
                                                      const float* __restrict__ esq,
                                                      const int* __restrict__ best_idx,
                                                      const float* __restrict__ gapv,
                                                      float* __restrict__ out_zq,
                                                      float* __restrict__ out_idx,
                                                      int* __restrict__ counts,
                                                      float* __restrict__ block_loss) {
  const int tid = threadIdx.x;
  const int wave = tid >> 6;
  const int lane = tid & 63;
  const int row = blockIdx.x * 4 + wave;

  int bidx = best_idx[row];
  float gap = gapv[row];

  if (gap < MARGIN) {
    // exact fp32 rescan of all 4096 codes for this row (rank on esq - 2*dot)
    f32x4 z4[16];
    const f32x4* zr = (const f32x4*)(z_e + (size_t)row * D);
#pragma unroll
    for (int i = 0; i < 16; ++i) z4[i] = zr[i];

    float bv = __builtin_inff();
    int bi = 0;
    for (int c = lane; c < K; c += 64) {
      const f32x4* er = (const f32x4*)(emb + (size_t)c * D);
      f32x4 a = {0.f, 0.f, 0.f, 0.f};
#pragma unroll
      for (int i = 0; i < 16; ++i) a = __builtin_elementwise_fma(er[i], z4[i], a);
      float dot = (a[0] + a[1]) + (a[2] + a[3]);
      float q = fmaf(-2.f, dot, esq[c]);
      if (q < bv) { bv = q; bi = c; }  // ascending c => first occurrence
    }
    // merge across lanes, smallest index wins ties
#pragma unroll
    for (int off = 32; off > 0; off >>= 1) {
      float ov = __shfl_down(bv, off);
      int oi = __shfl_down(bi, off);
      if (ov < bv || (ov == bv && oi < bi)) { bv = ov; bi = oi; }
    }
    bidx = __shfl(bi, 0);
  }

  float ze = z_e[(size_t)row * D + lane];
  float zq = emb[(size_t)bidx * D + lane];
  float st = ze + (zq - ze);  // straight-through, same formula as reference
  out_zq[(size_t)row * D + lane] = st;

  float diff = zq - ze;
  float sq = diff * diff;
#pragma unroll
  for (int off = 32; off > 0; off >>= 1) sq += __shfl_down(sq, off);

  __shared__ float ls[4];
  if (lane == 0) {
    ls[wave] = sq;
    out_idx[row] = (float)bidx;
    atomicAdd(&counts[bidx], 1);
  }
  __syncthreads();
  if (tid == 0) block_loss[blockIdx.x] = ls[0] + ls[1] + ls[2] + ls[3];
}

// ---------------------------------------------------------------------------
// Final scalars: commitment loss, perplexity, n_active. Single block.
// ---------------------------------------------------------------------------
__global__ __launch_bounds__(1024) void stats_kernel(const float* __restrict__ block_loss,
                                                     int nblocks,
                                                     const int* __restrict__ counts,
                                                     float* __restrict__ out_scalars,
                                                     int N) {
  const int tid = threadIdx.x;
  const int wave = tid >> 6;
  const int lane = tid & 63;

  float lsum = 0.f;
  for (int i = tid; i < nblocks; i += 1024) lsum += block_loss[i];

  float ent = 0.f;
  int act = 0;
  const float invN = 1.0f / (float)N;
  for (int k = tid; k < K; k += 1024) {
    float p = (float)counts[k] * invN;
    ent += p * logf(p + 1e-10f);
    act += (p > 0.001f) ? 1 : 0;
  }

#pragma unroll
  for (int off = 32; off > 0; off >>= 1) {
    lsum += __shfl_down(lsum, off);
    ent += __shfl_down(ent, off);
    act += __shfl_down(act, off);
  }

  __shared__ float sl[16], se[16];
  __shared__ int sa[16];
  if (lane == 0) { sl[wave] = lsum; se[wave] = ent; sa[wave] = act; }
  __syncthreads();
  if (tid == 0) {
    float L = 0.f, E = 0.f;
    int A = 0;
#pragma unroll
    for (int w = 0; w < 16; ++w) { L += sl[w]; E += se[w]; A += sa[w]; }
    out_scalars[0] = 0.25f * L / ((float)N * (float)D);  // commitment loss
    out_scalars[1] = expf(-E);                            // perplexity
    out_scalars[2] = (float)A;                            // n_active
  }
}

extern "C" void kernel_launch(void* const* d_in, const int* in_sizes, int n_in,
                              void* d_out, int out_size, void* d_ws, size_t ws_size,
                              hipStream_t stream) {
  const float* z_e = (const float*)d_in[0];
  const float* emb = (const float*)d_in[1];
  const int N = in_sizes[0] / D;  // 65536

  float* out = (float*)d_out;
  float* out_zq = out;
  float* out_idx = out + (size_t)N * D;
  float* out_scalars = out + (size_t)N * (D + 1);

  char* ws = (char*)d_ws;
  int* counts = (int*)ws;                                   // 16 KB
  float* esq = (float*)(ws + 16384);                        // 16 KB
  unsigned short* e_hi = (unsigned short*)(ws + 32768);     // 512 KB
  unsigned short* e_lo = (unsigned short*)(ws + 32768 + 524288);
  int* best_idx = (int*)(ws + 32768 + 2 * 524288);          // 256 KB
  float* gapv = (float*)(ws + 32768 + 2 * 524288 + 262144); // 256 KB
  float* block_loss = (float*)(ws + 32768 + 2 * 524288 + 2 * 262144);  // 64 KB

  hipMemsetAsync(counts, 0, K * sizeof(int), stream);

  esq_kernel<<<K / 256, 256, 0, stream>>>(emb, esq);
  esplit_kernel<<<K * D / 4 / 256, 256, 0, stream>>>(emb, e_hi, e_lo);
  dist_kernel<<<N / 128, 256, 0, stream>>>(z_e, e_hi, e_lo, esq, best_idx, gapv);
  combine_kernel<<<N / 4, 256, 0, stream>>>(z_e, emb, esq, best_idx, gapv, out_zq,
                                            out_idx, counts, block_loss);
  stats_kernel<<<1, 1024, 0, stream>>>(block_loss, N / 4, counts, out_scalars, N);
}